// Round 6
// baseline (137.210 us; speedup 1.0000x reference)
//
#include <hip/hip_runtime.h>
#include <cstddef>

#define IMG 256
#define HW 65536
#define NB 4
#define NC_IN 48
#define NHEADS 8
#define OHALO 18
#define OHP (OHALO*OHALO)  // 324

typedef short bf16x8 __attribute__((ext_vector_type(8)));
typedef float f32x4 __attribute__((ext_vector_type(4)));
typedef float f32x16 __attribute__((ext_vector_type(16)));

__device__ __forceinline__ unsigned short f2bf(float f) {
    unsigned int x = __float_as_uint(f);
    unsigned int r = (x + 0x7fffu + ((x >> 16) & 1u)) >> 16;
    return (unsigned short)r;
}

// bijective XCD-contiguous remap (m204)
__device__ __forceinline__ int xcd_map(int bid, int nwg) {
    const int q = nwg >> 3, r = nwg & 7;
    const int x = bid & 7, i = bid >> 3;
    return (x < r ? x * (q + 1) : r * (q + 1) + (x - r) * q) + i;
}

// ---------------------------------------------------------------------------
// K0: combined qk 3x3 weights, permuted+padded M layout.
//  slot s in [0,128): head=s>>4, sub=s&15 (q6 k6 pad4)
//  qcw[tap][s][e] = qk_dw[row,tap] * qk_w[row,e], bf16.
// ---------------------------------------------------------------------------
__global__ __launch_bounds__(256) void prep_qcw_kernel(
    const float* __restrict__ qk_w, const float* __restrict__ qk_dw,
    unsigned short* __restrict__ qcwb) {
    const int idx = blockIdx.x * 256 + threadIdx.x;
    if (idx >= 9 * 128 * 48) return;
    const int e = idx % 48;
    const int s = (idx / 48) & 127;
    const int tap = idx / (48 * 128);
    const int head = s >> 4, sub = s & 15;
    float v = 0.f;
    if (sub < 12) {
        const int row = (sub < 6) ? (head * 6 + sub) : (48 + head * 6 + (sub - 6));
        v = qk_dw[row * 9 + tap] * qk_w[row * 48 + e];
    }
    qcwb[idx] = f2bf(v);
}

// ---------------------------------------------------------------------------
// K1: qk path as ONE full 3x3 conv via MFMA + in-register Gram stats.
//  16x16 output tile, 18x18 halo bf16 in xs. A-fragments double-buffered in
//  registers across the 9-tap loop (prefetch tap t+1 before tap t's MFMAs).
// stats per b (384 f32): [0..47]=qq(h*6+c), [48..95]=kk, [96..]=h*36+cc*6+d
// ---------------------------------------------------------------------------
__global__ __launch_bounds__(256, 3) void fused_qk_stats_kernel(
    const float* __restrict__ fea0, const unsigned short* __restrict__ qcwb,
    float* __restrict__ stats) {
    __shared__ __align__(16) unsigned short xs[OHP][56];
    __shared__ __align__(16) unsigned short sg[4][16][72];
    __shared__ float sacc[384];

    const int tid = threadIdx.x;
    const int b = blockIdx.y;
    const int tile = xcd_map(blockIdx.x, 256);
    const int tx = tile & 15, ty = tile >> 4;
    const float* fb = fea0 + (size_t)b * NC_IN * HW;

    for (int i = tid; i < 384; i += 256) sacc[i] = 0.f;

    // stage 18x18 halo, 48 ch, bf16
    for (int hp = tid; hp < OHP; hp += 256) {
        const int hx = hp % OHALO, hy = hp / OHALO;
        const int gx = tx * 16 + hx - 1, gy = ty * 16 + hy - 1;
        const bool inb = ((unsigned)gx < (unsigned)IMG) && ((unsigned)gy < (unsigned)IMG);
        const int pix = inb ? (gy * IMG + gx) : 0;
#pragma unroll
        for (int j = 0; j < 6; ++j) {
            bf16x8 t;
#pragma unroll
            for (int c = 0; c < 8; ++c) {
                const float v = inb ? fb[(size_t)(j * 8 + c) * HW + pix] : 0.f;
                t[c] = (short)f2bf(v);
            }
            *(bf16x8*)&xs[hp][j * 8] = t;
        }
    }
    __syncthreads();

    const int wave = tid >> 6, lane = tid & 63;
    const int l31 = lane & 31, lhi = lane >> 5;
    const int opx0 = wave * 64 + l31, opx1 = opx0 + 32;
    const int r0 = (opx0 >> 4) * OHALO + (opx0 & 15);
    const int r1 = (opx1 >> 4) * OHALO + (opx1 & 15);
    const int fr = lane & 15, fg = lane >> 4;

#define DO_STATS(CA, CB, hbase)                                                   \
    {                                                                             \
        _Pragma("unroll")                                                         \
        for (int hh = 0; hh < 2; ++hh) {                                          \
            _Pragma("unroll")                                                     \
            for (int rq = 0; rq < 2; ++rq) {                                      \
                if (!(rq && lhi)) {                                               \
                    _Pragma("unroll")                                             \
                    for (int j = 0; j < 4; ++j) {                                 \
                        const int sub = j + 8 * rq + 4 * lhi;                     \
                        sg[wave][sub][l31] = f2bf(CA[hh * 8 + rq * 4 + j]);       \
                        sg[wave][sub][32 + l31] = f2bf(CB[hh * 8 + rq * 4 + j]);  \
                    }                                                             \
                }                                                                 \
            }                                                                     \
            asm volatile("s_waitcnt lgkmcnt(0)" ::: "memory");                    \
            __builtin_amdgcn_sched_barrier(0);                                    \
            const bf16x8 a0 = *(const bf16x8*)&sg[wave][fr][fg * 8];              \
            const bf16x8 a1 = *(const bf16x8*)&sg[wave][fr][32 + fg * 8];         \
            asm volatile("s_waitcnt lgkmcnt(0)" ::: "memory");                    \
            __builtin_amdgcn_sched_barrier(0);                                    \
            f32x4 c4 = {0.f, 0.f, 0.f, 0.f};                                      \
            c4 = __builtin_amdgcn_mfma_f32_16x16x32_bf16(a0, a0, c4, 0, 0, 0);    \
            c4 = __builtin_amdgcn_mfma_f32_16x16x32_bf16(a1, a1, c4, 0, 0, 0);    \
            const int h = (hbase) + hh;                                           \
            _Pragma("unroll")                                                     \
            for (int r = 0; r < 4; ++r) {                                         \
                const int crow = fg * 4 + r;                                      \
                const float vv = c4[r];                                           \
                if (crow < 6) {                                                   \
                    if (fr == crow) atomicAdd(&sacc[h * 6 + crow], vv);           \
                    else if (fr >= 6 && fr < 12)                                  \
                        atomicAdd(&sacc[96 + h * 36 + crow * 6 + (fr - 6)], vv);  \
                } else if (crow < 12 && fr == crow) {                             \
                    atomicAdd(&sacc[48 + h * 6 + (crow - 6)], vv);                \
                }                                                                 \
            }                                                                     \
        }                                                                         \
    }

#pragma unroll
    for (int p = 0; p < 2; ++p) {
        f32x16 C00, C01, C10, C11;
#pragma unroll
        for (int r = 0; r < 16; ++r) { C00[r] = 0.f; C01[r] = 0.f; C10[r] = 0.f; C11[r] = 0.f; }

        // A double-buffer: [buf][ks], buf toggles per tap (compile-time after unroll)
        bf16x8 a0b[2][3], a1b[2][3];
#pragma unroll
        for (int ks = 0; ks < 3; ++ks) {
            const int kb = ks * 16 + lhi * 8;
            a0b[0][ks] = *(const bf16x8*)&qcwb[((size_t)0 * 128 + p * 64 + l31) * 48 + kb];
            a1b[0][ks] = *(const bf16x8*)&qcwb[((size_t)0 * 128 + p * 64 + 32 + l31) * 48 + kb];
        }

#pragma unroll
        for (int t9 = 0; t9 < 9; ++t9) {
            const int cur = t9 & 1, nxt = cur ^ 1;
            if (t9 < 8) {
#pragma unroll
                for (int ks = 0; ks < 3; ++ks) {
                    const int kb = ks * 16 + lhi * 8;
                    a0b[nxt][ks] = *(const bf16x8*)&qcwb[((size_t)(t9 + 1) * 128 + p * 64 + l31) * 48 + kb];
                    a1b[nxt][ks] = *(const bf16x8*)&qcwb[((size_t)(t9 + 1) * 128 + p * 64 + 32 + l31) * 48 + kb];
                }
            }
            const int hoff = (t9 / 3) * OHALO + (t9 % 3);
#pragma unroll
            for (int ks = 0; ks < 3; ++ks) {
                const int kb = ks * 16 + lhi * 8;
                const bf16x8 b0 = *(const bf16x8*)&xs[r0 + hoff][kb];
                const bf16x8 b1 = *(const bf16x8*)&xs[r1 + hoff][kb];
                C00 = __builtin_amdgcn_mfma_f32_32x32x16_bf16(a0b[cur][ks], b0, C00, 0, 0, 0);
                C01 = __builtin_amdgcn_mfma_f32_32x32x16_bf16(a0b[cur][ks], b1, C01, 0, 0, 0);
                C10 = __builtin_amdgcn_mfma_f32_32x32x16_bf16(a1b[cur][ks], b0, C10, 0, 0, 0);
                C11 = __builtin_amdgcn_mfma_f32_32x32x16_bf16(a1b[cur][ks], b1, C11, 0, 0, 0);
            }
        }

        DO_STATS(C00, C01, p * 4 + 0)
        DO_STATS(C10, C11, p * 4 + 2)
    }
#undef DO_STATS

    __syncthreads();
    for (int i = tid; i < 384; i += 256) atomicAdd(&stats[b * 384 + i], sacc[i]);
}

// ---------------------------------------------------------------------------
// K2: softmax(6) -> W2 = proj . blockdiag(attn) -> combined v-side 3x3 weights
//     cw[tap][c][e] = sum_d W2[c][d] * v_w[d][e] * v_dw[d][tap]  (bf16)
// ---------------------------------------------------------------------------
__global__ __launch_bounds__(256) void softmax_w2_cw_kernel(
    const float* __restrict__ stats, const float* __restrict__ proj_w,
    const float* __restrict__ temperature, const float* __restrict__ v_w,
    const float* __restrict__ v_dw, unsigned short* __restrict__ cwb) {
    const int b = blockIdx.x;
    const int tid = threadIdx.x;
    __shared__ float attn[NHEADS * 36];
    __shared__ float W2s[48 * 48];
    const float* sb = stats + b * 384;

    if (tid < 48) {
        const int h = tid / 6, cc = tid % 6;
        float nq = fmaxf(sqrtf(sb[tid]), 1e-12f);
        const float tmp = temperature[h];
        float lo[6];
#pragma unroll
        for (int d = 0; d < 6; ++d) {
            const float nk = fmaxf(sqrtf(sb[48 + h * 6 + d]), 1e-12f);
            lo[d] = sb[96 + h * 36 + cc * 6 + d] / (nq * nk) * tmp;
        }
        float m = lo[0];
#pragma unroll
        for (int d = 1; d < 6; ++d) m = fmaxf(m, lo[d]);
        float s = 0.f;
#pragma unroll
        for (int d = 0; d < 6; ++d) { lo[d] = expf(lo[d] - m); s += lo[d]; }
        const float inv = 1.f / s;
#pragma unroll
        for (int d = 0; d < 6; ++d) attn[h * 36 + cc * 6 + d] = lo[d] * inv;
    }
    __syncthreads();

    for (int idx = tid; idx < 48 * 48; idx += 256) {
        const int c = idx / 48, dg = idx % 48;
        const int h = dg / 6, hd = dg % 6;
        float s = 0.f;
#pragma unroll
        for (int cc = 0; cc < 6; ++cc)
            s = fmaf(proj_w[c * 48 + h * 6 + cc], attn[h * 36 + cc * 6 + hd], s);
        W2s[idx] = s;
    }
    __syncthreads();

    for (int p = 0; p < 9; ++p) {
        const int pair = p * 256 + tid;
        const int c = pair / 48, e = pair % 48;
        float acc[9];
#pragma unroll
        for (int t = 0; t < 9; ++t) acc[t] = 0.f;
        for (int d = 0; d < 48; ++d) {
            const float wv = W2s[c * 48 + d] * v_w[d * 48 + e];
#pragma unroll
            for (int t = 0; t < 9; ++t)
                acc[t] = fmaf(wv, v_dw[d * 9 + t], acc[t]);
        }
#pragma unroll
        for (int t = 0; t < 9; ++t)
            cwb[(size_t)b * 20736 + (size_t)(t * 48 + c) * 48 + e] = f2bf(acc[t]);
    }
}

// ---------------------------------------------------------------------------
// K3: out = cw (*) fea1 : full 3x3 conv 48->48 via MFMA, A double-buffered.
// ---------------------------------------------------------------------------
__global__ __launch_bounds__(256, 3) void conv3x3_out_kernel(
    const float* __restrict__ fea1, const unsigned short* __restrict__ cwb,
    float* __restrict__ out) {
    __shared__ __align__(16) unsigned short xs[OHP][56];

    const int tid = threadIdx.x;
    const int b = blockIdx.y;
    const int tile = xcd_map(blockIdx.x, 256);
    const int tx = tile & 15, ty = tile >> 4;
    const float* fb = fea1 + (size_t)b * NC_IN * HW;

    for (int hp = tid; hp < OHP; hp += 256) {
        const int hx = hp % OHALO, hy = hp / OHALO;
        const int gx = tx * 16 + hx - 1, gy = ty * 16 + hy - 1;
        const bool inb = ((unsigned)gx < (unsigned)IMG) && ((unsigned)gy < (unsigned)IMG);
        const int pix = inb ? (gy * IMG + gx) : 0;
#pragma unroll
        for (int j = 0; j < 6; ++j) {
            bf16x8 t;
#pragma unroll
            for (int c = 0; c < 8; ++c) {
                const float v = inb ? fb[(size_t)(j * 8 + c) * HW + pix] : 0.f;
                t[c] = (short)f2bf(v);
            }
            *(bf16x8*)&xs[hp][j * 8] = t;
        }
    }
    __syncthreads();

    const int wave = tid >> 6, lane = tid & 63;
    const int l31 = lane & 31, lhi = lane >> 5;
    const int opx0 = wave * 64 + l31, opx1 = opx0 + 32;
    const int r0 = (opx0 >> 4) * OHALO + (opx0 & 15);
    const int r1 = (opx1 >> 4) * OHALO + (opx1 & 15);
    const unsigned short* cb = cwb + (size_t)b * 20736;
    const bool m1ok = l31 < 16;

    f32x16 C00, C01, C10, C11;
#pragma unroll
    for (int r = 0; r < 16; ++r) { C00[r] = 0.f; C01[r] = 0.f; C10[r] = 0.f; C11[r] = 0.f; }

    bf16x8 zf;
#pragma unroll
    for (int j = 0; j < 8; ++j) zf[j] = 0;

    bf16x8 a0b[2][3], a1b[2][3];
#pragma unroll
    for (int ks = 0; ks < 3; ++ks) {
        const int kb = ks * 16 + lhi * 8;
        a0b[0][ks] = *(const bf16x8*)&cb[(size_t)(0 * 48 + l31) * 48 + kb];
        a1b[0][ks] = m1ok ? *(const bf16x8*)&cb[(size_t)(0 * 48 + 32 + l31) * 48 + kb] : zf;
    }

#pragma unroll
    for (int t9 = 0; t9 < 9; ++t9) {
        const int cur = t9 & 1, nxt = cur ^ 1;
        if (t9 < 8) {
#pragma unroll
            for (int ks = 0; ks < 3; ++ks) {
                const int kb = ks * 16 + lhi * 8;
                a0b[nxt][ks] = *(const bf16x8*)&cb[(size_t)((t9 + 1) * 48 + l31) * 48 + kb];
                a1b[nxt][ks] = m1ok ? *(const bf16x8*)&cb[(size_t)((t9 + 1) * 48 + 32 + l31) * 48 + kb] : zf;
            }
        }
        const int hoff = (t9 / 3) * OHALO + (t9 % 3);
#pragma unroll
        for (int ks = 0; ks < 3; ++ks) {
            const int kb = ks * 16 + lhi * 8;
            const bf16x8 b0 = *(const bf16x8*)&xs[r0 + hoff][kb];
            const bf16x8 b1 = *(const bf16x8*)&xs[r1 + hoff][kb];
            C00 = __builtin_amdgcn_mfma_f32_32x32x16_bf16(a0b[cur][ks], b0, C00, 0, 0, 0);
            C01 = __builtin_amdgcn_mfma_f32_32x32x16_bf16(a0b[cur][ks], b1, C01, 0, 0, 0);
            C10 = __builtin_amdgcn_mfma_f32_32x32x16_bf16(a1b[cur][ks], b0, C10, 0, 0, 0);
            C11 = __builtin_amdgcn_mfma_f32_32x32x16_bf16(a1b[cur][ks], b1, C11, 0, 0, 0);
        }
    }

    float* ob = out + (size_t)b * NC_IN * HW;
    const int g0 = (ty * 16 + (opx0 >> 4)) * IMG + tx * 16 + (opx0 & 15);
    const int g1 = (ty * 16 + (opx1 >> 4)) * IMG + tx * 16 + (opx1 & 15);
#pragma unroll
    for (int r = 0; r < 16; ++r) {
        const int row = (r & 3) + 8 * (r >> 2) + 4 * lhi;
        ob[(size_t)row * HW + g0] = C00[r];
        ob[(size_t)row * HW + g1] = C01[r];
        const int row1 = 32 + row;
        if (row1 < 48) {
            ob[(size_t)row1 * HW + g0] = C10[r];
            ob[(size_t)row1 * HW + g1] = C11[r];
        }
    }
}

// ---------------------------------------------------------------------------
extern "C" void kernel_launch(void* const* d_in, const int* in_sizes, int n_in,
                              void* d_out, int out_size, void* d_ws, size_t ws_size,
                              hipStream_t stream) {
    const float* fea0 = (const float*)d_in[0];
    const float* fea1 = (const float*)d_in[1];
    const float* qk_w = (const float*)d_in[2];
    const float* qk_dw = (const float*)d_in[3];
    const float* v_w = (const float*)d_in[4];
    const float* v_dw = (const float*)d_in[5];
    const float* proj_w = (const float*)d_in[6];
    const float* temperature = (const float*)d_in[7];
    float* out = (float*)d_out;

    char* ws = (char*)d_ws;
    float* stats = (float*)ws;                                    // 6144 B
    unsigned short* cwb = (unsigned short*)(ws + 8192);           // 165888 B
    unsigned short* qcwb = (unsigned short*)(ws + 8192 + 165888); // 110592 B

    hipMemsetAsync(stats, 0, (size_t)NB * 384 * sizeof(float), stream);

    prep_qcw_kernel<<<216, 256, 0, stream>>>(qk_w, qk_dw, qcwb);
    fused_qk_stats_kernel<<<dim3(256, NB), 256, 0, stream>>>(fea0, qcwb, stats);
    softmax_w2_cw_kernel<<<NB, 256, 0, stream>>>(stats, proj_w, temperature, v_w, v_dw, cwb);
    conv3x3_out_kernel<<<dim3(256, NB), 256, 0, stream>>>(fea1, cwb, out);
}

// Round 7
// 121.947 us; speedup vs baseline: 1.1252x; 1.1252x over previous
//
#include <hip/hip_runtime.h>
#include <cstddef>

#define IMG 256
#define HW 65536
#define NB 4
#define NHEADS 8
#define TW 32
#define TH 16
#define HAW 34
#define HAH 18
#define HP2 (HAW*HAH)   // 612
#define NTILE 128       // (256/32)*(256/16)
#define XSP 24          // xs row pitch in ushorts (48 B: 16B-aligned)

typedef short bf16x8 __attribute__((ext_vector_type(8)));
typedef float f32x4 __attribute__((ext_vector_type(4)));
typedef float f32x16 __attribute__((ext_vector_type(16)));

__device__ __forceinline__ unsigned short f2bf(float f) {
    unsigned int x = __float_as_uint(f);
    unsigned int r = (x + 0x7fffu + ((x >> 16) & 1u)) >> 16;
    return (unsigned short)r;
}

// bijective XCD-contiguous remap (m204); NTILE%8==0 -> clean
__device__ __forceinline__ int xcd_map(int bid, int nwg) {
    const int q = nwg >> 3, r = nwg & 7;
    const int x = bid & 7, i = bid >> 3;
    return (x < r ? x * (q + 1) : r * (q + 1) + (x - r) * q) + i;
}

// ---------------------------------------------------------------------------
// K0: combined qk 3x3 weights, layout [tap][ks][slot128][16]
//  slot s: head=s>>4, sub=s&15 (q6 k6 pad4)
//  val = qk_dw[row,tap] * qk_w[row, ks*16+e16]
// ---------------------------------------------------------------------------
__global__ __launch_bounds__(256) void prep_qcw_kernel(
    const float* __restrict__ qk_w, const float* __restrict__ qk_dw,
    unsigned short* __restrict__ qcwb) {
    const int idx = blockIdx.x * 256 + threadIdx.x;   // 27*128*16 = 55296 exact
    const int e16 = idx & 15;
    const int slot = (idx >> 4) & 127;
    const int tk = idx >> 11;          // tap*3+ks
    const int ks = tk % 3;
    const int head = slot >> 4, sub = slot & 15;
    float v = 0.f;
    if (sub < 12) {
        const int row = (sub < 6) ? (head * 6 + sub) : (48 + head * 6 + (sub - 6));
        v = qk_dw[row * 9 + tk / 3] * qk_w[row * 48 + ks * 16 + e16];
    }
    qcwb[idx] = f2bf(v);
}

// ---------------------------------------------------------------------------
// K1: qk path = full 3x3 conv via MFMA, 32x16 tile, 8 waves (512 thr).
//  wave w: p = w>>2 (M-half of 128 permuted slots), g = w&3 (4 tile rows).
//  per wave: 2 m-frags x 4 n-frags (one image row each) = 8 f32x16 accums.
//  3 ks-phases: stage xs[612][24] (16ch bf16 slice) -> 9 taps x 16 MFMA.
//  Stats from C via 16x16x32 Gram MFMA on per-wave sg staging + atomics.
// stats per b (384 f32): [0..47]=qq(h*6+c), [48..95]=kk, [96..]=h*36+cc*6+d
// ---------------------------------------------------------------------------
__global__ __launch_bounds__(512, 2) void fused_qk_stats_kernel(
    const float* __restrict__ fea0, const unsigned short* __restrict__ qcwb,
    float* __restrict__ stats) {
    __shared__ __align__(16) unsigned short xs[HP2][XSP];
    __shared__ __align__(16) unsigned short sg[8][16][72];
    __shared__ float sacc[384];

    const int tid = threadIdx.x;
    const int b = blockIdx.y;
    const int tile = xcd_map(blockIdx.x, NTILE);
    const int tx = tile & 7, ty = tile >> 3;
    const float* fb = fea0 + (size_t)b * 48 * HW;

    for (int i = tid; i < 384; i += 512) sacc[i] = 0.f;

    const int wave = tid >> 6, lane = tid & 63;
    const int l31 = lane & 31, lhi = lane >> 5;
    const int p = wave >> 2, g = wave & 3;

    f32x16 C[2][4];
#pragma unroll
    for (int m = 0; m < 2; ++m)
#pragma unroll
        for (int nf = 0; nf < 4; ++nf)
#pragma unroll
            for (int r = 0; r < 16; ++r) C[m][nf][r] = 0.f;

#pragma unroll
    for (int ks = 0; ks < 3; ++ks) {
        __syncthreads();   // previous phase's xs reads complete
        for (int hp = tid; hp < HP2; hp += 512) {
            const int hx = hp % HAW, hy = hp / HAW;
            const int gx = tx * TW + hx - 1, gy = ty * TH + hy - 1;
            const bool inb = ((unsigned)gx < (unsigned)IMG) && ((unsigned)gy < (unsigned)IMG);
            const int pix = inb ? (gy * IMG + gx) : 0;
            bf16x8 t0, t1;
#pragma unroll
            for (int c = 0; c < 8; ++c) {
                t0[c] = (short)f2bf(inb ? fb[(size_t)(ks * 16 + c) * HW + pix] : 0.f);
                t1[c] = (short)f2bf(inb ? fb[(size_t)(ks * 16 + 8 + c) * HW + pix] : 0.f);
            }
            *(bf16x8*)&xs[hp][0] = t0;
            *(bf16x8*)&xs[hp][8] = t1;
        }
        __syncthreads();

#pragma unroll
        for (int tap = 0; tap < 9; ++tap) {
            const int dy = tap / 3, dx = tap % 3;
            const bf16x8 a0 = *(const bf16x8*)&qcwb[(size_t)((tap * 3 + ks) * 128 + p * 64 + l31) * 16 + lhi * 8];
            const bf16x8 a1 = *(const bf16x8*)&qcwb[(size_t)((tap * 3 + ks) * 128 + p * 64 + 32 + l31) * 16 + lhi * 8];
#pragma unroll
            for (int nf = 0; nf < 4; ++nf) {
                const int hrow = (4 * g + nf + dy) * HAW + l31 + dx;
                const bf16x8 bb = *(const bf16x8*)&xs[hrow][lhi * 8];
                C[0][nf] = __builtin_amdgcn_mfma_f32_32x32x16_bf16(a0, bb, C[0][nf], 0, 0, 0);
                C[1][nf] = __builtin_amdgcn_mfma_f32_32x32x16_bf16(a1, bb, C[1][nf], 0, 0, 0);
            }
        }
    }

    const int fr = lane & 15, fg = lane >> 4;

#define DO_STATS(CA, CB, hbase)                                                   \
    {                                                                             \
        _Pragma("unroll")                                                         \
        for (int hh = 0; hh < 2; ++hh) {                                          \
            _Pragma("unroll")                                                     \
            for (int rq = 0; rq < 2; ++rq) {                                      \
                if (!(rq && lhi)) {                                               \
                    _Pragma("unroll")                                             \
                    for (int j = 0; j < 4; ++j) {                                 \
                        const int sub = j + 8 * rq + 4 * lhi;                     \
                        sg[wave][sub][l31] = f2bf(CA[hh * 8 + rq * 4 + j]);       \
                        sg[wave][sub][32 + l31] = f2bf(CB[hh * 8 + rq * 4 + j]);  \
                    }                                                             \
                }                                                                 \
            }                                                                     \
            asm volatile("s_waitcnt lgkmcnt(0)" ::: "memory");                    \
            __builtin_amdgcn_sched_barrier(0);                                    \
            const bf16x8 a0 = *(const bf16x8*)&sg[wave][fr][fg * 8];              \
            const bf16x8 a1 = *(const bf16x8*)&sg[wave][fr][32 + fg * 8];         \
            asm volatile("s_waitcnt lgkmcnt(0)" ::: "memory");                    \
            __builtin_amdgcn_sched_barrier(0);                                    \
            f32x4 c4 = {0.f, 0.f, 0.f, 0.f};                                      \
            c4 = __builtin_amdgcn_mfma_f32_16x16x32_bf16(a0, a0, c4, 0, 0, 0);    \
            c4 = __builtin_amdgcn_mfma_f32_16x16x32_bf16(a1, a1, c4, 0, 0, 0);    \
            const int h = (hbase) + hh;                                           \
            _Pragma("unroll")                                                     \
            for (int r = 0; r < 4; ++r) {                                         \
                const int crow = fg * 4 + r;                                      \
                const float vv = c4[r];                                           \
                if (crow < 6) {                                                   \
                    if (fr == crow) atomicAdd(&sacc[h * 6 + crow], vv);           \
                    else if (fr >= 6 && fr < 12)                                  \
                        atomicAdd(&sacc[96 + h * 36 + crow * 6 + (fr - 6)], vv);  \
                } else if (crow < 12 && fr == crow) {                             \
                    atomicAdd(&sacc[48 + h * 6 + (crow - 6)], vv);                \
                }                                                                 \
            }                                                                     \
        }                                                                         \
    }

#pragma unroll
    for (int m = 0; m < 2; ++m) {
        DO_STATS(C[m][0], C[m][1], p * 4 + m * 2)
        DO_STATS(C[m][2], C[m][3], p * 4 + m * 2)
    }
#undef DO_STATS

    __syncthreads();
    for (int i = tid; i < 384; i += 512) atomicAdd(&stats[b * 384 + i], sacc[i]);
}

// ---------------------------------------------------------------------------
// K2: softmax(6) -> W2 = proj . blockdiag(attn) -> combined v-side weights
//  cwb layout [tap][ks][slot64][16] (slots 48..63 zero), bf16.
// ---------------------------------------------------------------------------
__global__ __launch_bounds__(256) void softmax_w2_cw_kernel(
    const float* __restrict__ stats, const float* __restrict__ proj_w,
    const float* __restrict__ temperature, const float* __restrict__ v_w,
    const float* __restrict__ v_dw, unsigned short* __restrict__ cwb) {
    const int b = blockIdx.x;
    const int tid = threadIdx.x;
    __shared__ float attn[NHEADS * 36];
    __shared__ float W2s[48 * 48];
    const float* sb = stats + b * 384;

    if (tid < 48) {
        const int h = tid / 6, cc = tid % 6;
        float nq = fmaxf(sqrtf(sb[tid]), 1e-12f);
        const float tmp = temperature[h];
        float lo[6];
#pragma unroll
        for (int d = 0; d < 6; ++d) {
            const float nk = fmaxf(sqrtf(sb[48 + h * 6 + d]), 1e-12f);
            lo[d] = sb[96 + h * 36 + cc * 6 + d] / (nq * nk) * tmp;
        }
        float m = lo[0];
#pragma unroll
        for (int d = 1; d < 6; ++d) m = fmaxf(m, lo[d]);
        float s = 0.f;
#pragma unroll
        for (int d = 0; d < 6; ++d) { lo[d] = expf(lo[d] - m); s += lo[d]; }
        const float inv = 1.f / s;
#pragma unroll
        for (int d = 0; d < 6; ++d) attn[h * 36 + cc * 6 + d] = lo[d] * inv;
    }
    __syncthreads();

    for (int idx = tid; idx < 48 * 48; idx += 256) {
        const int c = idx / 48, dg = idx % 48;
        const int h = dg / 6, hd = dg % 6;
        float s = 0.f;
#pragma unroll
        for (int cc = 0; cc < 6; ++cc)
            s = fmaf(proj_w[c * 48 + h * 6 + cc], attn[h * 36 + cc * 6 + hd], s);
        W2s[idx] = s;
    }
    __syncthreads();

    unsigned short* cb = cwb + (size_t)b * 27648;
    // real slots: 2304 (c,e) pairs, 9 per thread
    for (int pp = 0; pp < 9; ++pp) {
        const int pair = pp * 256 + tid;
        const int c = pair / 48, e = pair % 48;
        float acc[9];
#pragma unroll
        for (int t = 0; t < 9; ++t) acc[t] = 0.f;
        for (int d = 0; d < 48; ++d) {
            const float wv = W2s[c * 48 + d] * v_w[d * 48 + e];
#pragma unroll
            for (int t = 0; t < 9; ++t)
                acc[t] = fmaf(wv, v_dw[d * 9 + t], acc[t]);
        }
#pragma unroll
        for (int t = 0; t < 9; ++t)
            cb[(size_t)((t * 3 + (e >> 4)) * 64 + c) * 16 + (e & 15)] = f2bf(acc[t]);
    }
    // pad slots 48..63 -> zero  (27*16*16 = 6912 elems)
    for (int i = tid; i < 6912; i += 256) {
        const int e16 = i & 15;
        const int cp = 48 + ((i >> 4) & 15);
        const int tk = i >> 8;
        cb[(size_t)(tk * 64 + cp) * 16 + e16] = 0;
    }
}

// ---------------------------------------------------------------------------
// K3: out = cw (*) fea1, 32x16 tile, 8 waves. wave: m = w&1 (32 out-ch),
//  g = w>>1 (4 tile rows). 1 m x 4 n = 4 accums. A:MFMA = 1:4.
// ---------------------------------------------------------------------------
__global__ __launch_bounds__(512, 2) void conv3x3_out_kernel(
    const float* __restrict__ fea1, const unsigned short* __restrict__ cwb,
    float* __restrict__ out) {
    __shared__ __align__(16) unsigned short xs[HP2][XSP];

    const int tid = threadIdx.x;
    const int b = blockIdx.y;
    const int tile = xcd_map(blockIdx.x, NTILE);
    const int tx = tile & 7, ty = tile >> 3;
    const float* fb = fea1 + (size_t)b * 48 * HW;
    const unsigned short* cb = cwb + (size_t)b * 27648;

    const int wave = tid >> 6, lane = tid & 63;
    const int l31 = lane & 31, lhi = lane >> 5;
    const int m = wave & 1, g = wave >> 1;

    f32x16 C[4];
#pragma unroll
    for (int nf = 0; nf < 4; ++nf)
#pragma unroll
        for (int r = 0; r < 16; ++r) C[nf][r] = 0.f;

#pragma unroll
    for (int ks = 0; ks < 3; ++ks) {
        __syncthreads();
        for (int hp = tid; hp < HP2; hp += 512) {
            const int hx = hp % HAW, hy = hp / HAW;
            const int gx = tx * TW + hx - 1, gy = ty * TH + hy - 1;
            const bool inb = ((unsigned)gx < (unsigned)IMG) && ((unsigned)gy < (unsigned)IMG);
            const int pix = inb ? (gy * IMG + gx) : 0;
            bf16x8 t0, t1;
#pragma unroll
            for (int c = 0; c < 8; ++c) {
                t0[c] = (short)f2bf(inb ? fb[(size_t)(ks * 16 + c) * HW + pix] : 0.f);
                t1[c] = (short)f2bf(inb ? fb[(size_t)(ks * 16 + 8 + c) * HW + pix] : 0.f);
            }
            *(bf16x8*)&xs[hp][0] = t0;
            *(bf16x8*)&xs[hp][8] = t1;
        }
        __syncthreads();

#pragma unroll
        for (int tap = 0; tap < 9; ++tap) {
            const int dy = tap / 3, dx = tap % 3;
            const bf16x8 a = *(const bf16x8*)&cb[(size_t)((tap * 3 + ks) * 64 + m * 32 + l31) * 16 + lhi * 8];
#pragma unroll
            for (int nf = 0; nf < 4; ++nf) {
                const int hrow = (4 * g + nf + dy) * HAW + l31 + dx;
                const bf16x8 bb = *(const bf16x8*)&xs[hrow][lhi * 8];
                C[nf] = __builtin_amdgcn_mfma_f32_32x32x16_bf16(a, bb, C[nf], 0, 0, 0);
            }
        }
    }

    float* ob = out + (size_t)b * 48 * HW;
#pragma unroll
    for (int nf = 0; nf < 4; ++nf) {
        const int gpx = (ty * TH + 4 * g + nf) * IMG + tx * TW + l31;
#pragma unroll
        for (int r = 0; r < 16; ++r) {
            const int och = m * 32 + (r & 3) + 8 * (r >> 2) + 4 * lhi;
            if (m == 0 || r < 8) ob[(size_t)och * HW + gpx] = C[nf][r];
        }
    }
}

// ---------------------------------------------------------------------------
extern "C" void kernel_launch(void* const* d_in, const int* in_sizes, int n_in,
                              void* d_out, int out_size, void* d_ws, size_t ws_size,
                              hipStream_t stream) {
    const float* fea0 = (const float*)d_in[0];
    const float* fea1 = (const float*)d_in[1];
    const float* qk_w = (const float*)d_in[2];
    const float* qk_dw = (const float*)d_in[3];
    const float* v_w = (const float*)d_in[4];
    const float* v_dw = (const float*)d_in[5];
    const float* proj_w = (const float*)d_in[6];
    const float* temperature = (const float*)d_in[7];
    float* out = (float*)d_out;

    char* ws = (char*)d_ws;
    float* stats = (float*)ws;                                     // 6144 B
    unsigned short* cwb = (unsigned short*)(ws + 8192);            // 4*27648*2 = 221184 B
    unsigned short* qcwb = (unsigned short*)(ws + 8192 + 221184);  // 110592 B

    hipMemsetAsync(stats, 0, (size_t)NB * 384 * sizeof(float), stream);

    prep_qcw_kernel<<<216, 256, 0, stream>>>(qk_w, qk_dw, qcwb);
    fused_qk_stats_kernel<<<dim3(NTILE, NB), 512, 0, stream>>>(fea0, qcwb, stats);
    softmax_w2_cw_kernel<<<NB, 256, 0, stream>>>(stats, proj_w, temperature, v_w, v_dw, cwb);
    conv3x3_out_kernel<<<dim3(NTILE, NB), 512, 0, stream>>>(fea1, cwb, out);
}

// Round 8
// 119.560 us; speedup vs baseline: 1.1476x; 1.0200x over previous
//
#include <hip/hip_runtime.h>
#include <cstddef>

#define IMG 256
#define HW 65536
#define NB 4
#define NHEADS 8
#define TW 32
#define TH 8
#define HAW 34
#define HAH 10
#define HP2 (HAW*HAH)   // 340
#define NTILE 256       // (256/32)*(256/8)
#define XSP 28          // xs row pitch in ushorts (56 B -> 2-way max on b128 reads)

typedef short bf16x8 __attribute__((ext_vector_type(8)));
typedef float f32x4 __attribute__((ext_vector_type(4)));
typedef float f32x16 __attribute__((ext_vector_type(16)));

__device__ __forceinline__ unsigned short f2bf(float f) {
    unsigned int x = __float_as_uint(f);
    unsigned int r = (x + 0x7fffu + ((x >> 16) & 1u)) >> 16;
    return (unsigned short)r;
}

// bijective XCD-contiguous remap (m204)
__device__ __forceinline__ int xcd_map(int bid, int nwg) {
    const int q = nwg >> 3, r = nwg & 7;
    const int x = bid & 7, i = bid >> 3;
    return (x < r ? x * (q + 1) : r * (q + 1) + (x - r) * q) + i;
}

// ---------------------------------------------------------------------------
// K0: combined qk 3x3 weights, layout [tap][ks][slot128][16]
//  slot s: head=s>>4, sub=s&15 (q6 k6 pad4); val = qk_dw[row,tap]*qk_w[row,ks*16+e]
// ---------------------------------------------------------------------------
__global__ __launch_bounds__(256) void prep_qcw_kernel(
    const float* __restrict__ qk_w, const float* __restrict__ qk_dw,
    unsigned short* __restrict__ qcwb) {
    const int idx = blockIdx.x * 256 + threadIdx.x;   // 27*128*16 = 55296 exact
    const int e16 = idx & 15;
    const int slot = (idx >> 4) & 127;
    const int tk = idx >> 11;          // tap*3+ks
    const int ks = tk % 3;
    const int head = slot >> 4, sub = slot & 15;
    float v = 0.f;
    if (sub < 12) {
        const int row = (sub < 6) ? (head * 6 + sub) : (48 + head * 6 + (sub - 6));
        v = qk_dw[row * 9 + tk / 3] * qk_w[row * 48 + ks * 16 + e16];
    }
    qcwb[idx] = f2bf(v);
}

// ---------------------------------------------------------------------------
// K1: qk conv + stats. 32x8 tile, 256 thr (4 waves), M-half p per BLOCK.
//  wave: m = w&1 (32 slots of the p-half), g = w>>1 (rows 4g..4g+3).
//  Per wave: 1 A-load/tap-ks, 4 accums (64 AGPR). 3 ks-phases stage
//  xs[340][28] (16ch bf16). Sibling p-blocks share halo via same-XCD L2.
// stats per b (384 f32): [0..47]=qq(h*6+c), [48..95]=kk, [96..]=h*36+cc*6+d
// ---------------------------------------------------------------------------
__global__ __launch_bounds__(256, 4) void fused_qk_stats_kernel(
    const float* __restrict__ fea0, const unsigned short* __restrict__ qcwb,
    float* __restrict__ stats) {
    __shared__ __align__(16) unsigned short xs[HP2][XSP];
    __shared__ __align__(16) unsigned short sg[4][16][72];
    __shared__ float sacc[384];

    const int tid = threadIdx.x;
    const int b = blockIdx.y;
    const int mp = xcd_map(blockIdx.x, 2 * NTILE);
    const int tile = mp >> 1, p = mp & 1;
    const int tx = tile & 7, ty = tile >> 3;
    const float* fb = fea0 + (size_t)b * 48 * HW;

    for (int i = tid; i < 384; i += 256) sacc[i] = 0.f;

    const int wave = tid >> 6, lane = tid & 63;
    const int l31 = lane & 31, lhi = lane >> 5;
    const int m = wave & 1, g = wave >> 1;

    f32x16 C[4];
#pragma unroll
    for (int nf = 0; nf < 4; ++nf)
#pragma unroll
        for (int r = 0; r < 16; ++r) C[nf][r] = 0.f;

#pragma unroll
    for (int ks = 0; ks < 3; ++ks) {
        __syncthreads();   // previous phase's xs reads complete
        for (int hp = tid; hp < HP2; hp += 256) {
            const int hx = hp % HAW, hy = hp / HAW;
            const int gx = tx * TW + hx - 1, gy = ty * TH + hy - 1;
            const bool inb = ((unsigned)gx < (unsigned)IMG) && ((unsigned)gy < (unsigned)IMG);
            const int pix = inb ? (gy * IMG + gx) : 0;
            bf16x8 t0, t1;
#pragma unroll
            for (int c = 0; c < 8; ++c) {
                t0[c] = (short)f2bf(inb ? fb[(size_t)(ks * 16 + c) * HW + pix] : 0.f);
                t1[c] = (short)f2bf(inb ? fb[(size_t)(ks * 16 + 8 + c) * HW + pix] : 0.f);
            }
            *(bf16x8*)&xs[hp][0] = t0;
            *(bf16x8*)&xs[hp][8] = t1;
        }
        __syncthreads();

#pragma unroll
        for (int tap = 0; tap < 9; ++tap) {
            const int dy = tap / 3, dx = tap % 3;
            const bf16x8 a = *(const bf16x8*)&qcwb[(size_t)((tap * 3 + ks) * 128 + p * 64 + m * 32 + l31) * 16 + lhi * 8];
#pragma unroll
            for (int nf = 0; nf < 4; ++nf) {
                const int hrow = (4 * g + nf + dy) * HAW + l31 + dx;
                const bf16x8 bb = *(const bf16x8*)&xs[hrow][lhi * 8];
                C[nf] = __builtin_amdgcn_mfma_f32_32x32x16_bf16(a, bb, C[nf], 0, 0, 0);
            }
        }
    }

    const int fr = lane & 15, fg = lane >> 4;

#define DO_STATS(CA, CB, hbase)                                                   \
    {                                                                             \
        _Pragma("unroll")                                                         \
        for (int hh = 0; hh < 2; ++hh) {                                          \
            _Pragma("unroll")                                                     \
            for (int rq = 0; rq < 2; ++rq) {                                      \
                if (!(rq && lhi)) {                                               \
                    _Pragma("unroll")                                             \
                    for (int j = 0; j < 4; ++j) {                                 \
                        const int sub = j + 8 * rq + 4 * lhi;                     \
                        sg[wave][sub][l31] = f2bf(CA[hh * 8 + rq * 4 + j]);       \
                        sg[wave][sub][32 + l31] = f2bf(CB[hh * 8 + rq * 4 + j]);  \
                    }                                                             \
                }                                                                 \
            }                                                                     \
            asm volatile("s_waitcnt lgkmcnt(0)" ::: "memory");                    \
            __builtin_amdgcn_sched_barrier(0);                                    \
            const bf16x8 a0 = *(const bf16x8*)&sg[wave][fr][fg * 8];              \
            const bf16x8 a1 = *(const bf16x8*)&sg[wave][fr][32 + fg * 8];         \
            asm volatile("s_waitcnt lgkmcnt(0)" ::: "memory");                    \
            __builtin_amdgcn_sched_barrier(0);                                    \
            f32x4 c4 = {0.f, 0.f, 0.f, 0.f};                                      \
            c4 = __builtin_amdgcn_mfma_f32_16x16x32_bf16(a0, a0, c4, 0, 0, 0);    \
            c4 = __builtin_amdgcn_mfma_f32_16x16x32_bf16(a1, a1, c4, 0, 0, 0);    \
            const int h = (hbase) + hh;                                           \
            _Pragma("unroll")                                                     \
            for (int r = 0; r < 4; ++r) {                                         \
                const int crow = fg * 4 + r;                                      \
                const float vv = c4[r];                                           \
                if (crow < 6) {                                                   \
                    if (fr == crow) atomicAdd(&sacc[h * 6 + crow], vv);           \
                    else if (fr >= 6 && fr < 12)                                  \
                        atomicAdd(&sacc[96 + h * 36 + crow * 6 + (fr - 6)], vv);  \
                } else if (crow < 12 && fr == crow) {                             \
                    atomicAdd(&sacc[48 + h * 6 + (crow - 6)], vv);                \
                }                                                                 \
            }                                                                     \
        }                                                                         \
    }

    DO_STATS(C[0], C[1], p * 4 + m * 2)
    DO_STATS(C[2], C[3], p * 4 + m * 2)
#undef DO_STATS

    __syncthreads();
    // flush only this p-half's 192 stats entries
    for (int i = tid; i < 192; i += 256) {
        int idx;
        if (i < 24) idx = p * 24 + i;
        else if (i < 48) idx = 48 + p * 24 + (i - 24);
        else idx = 96 + p * 144 + (i - 48);
        atomicAdd(&stats[b * 384 + idx], sacc[idx]);
    }
}

// ---------------------------------------------------------------------------
// K2: softmax(6) -> W2 = proj . blockdiag(attn) -> combined v-side weights
//  cwb layout [tap][ks][slot64][16] (slots 48..63 zero), bf16.
// ---------------------------------------------------------------------------
__global__ __launch_bounds__(256) void softmax_w2_cw_kernel(
    const float* __restrict__ stats, const float* __restrict__ proj_w,
    const float* __restrict__ temperature, const float* __restrict__ v_w,
    const float* __restrict__ v_dw, unsigned short* __restrict__ cwb) {
    const int b = blockIdx.x;
    const int tid = threadIdx.x;
    __shared__ float attn[NHEADS * 36];
    __shared__ float W2s[48 * 48];
    const float* sb = stats + b * 384;

    if (tid < 48) {
        const int h = tid / 6, cc = tid % 6;
        float nq = fmaxf(sqrtf(sb[tid]), 1e-12f);
        const float tmp = temperature[h];
        float lo[6];
#pragma unroll
        for (int d = 0; d < 6; ++d) {
            const float nk = fmaxf(sqrtf(sb[48 + h * 6 + d]), 1e-12f);
            lo[d] = sb[96 + h * 36 + cc * 6 + d] / (nq * nk) * tmp;
        }
        float m = lo[0];
#pragma unroll
        for (int d = 1; d < 6; ++d) m = fmaxf(m, lo[d]);
        float s = 0.f;
#pragma unroll
        for (int d = 0; d < 6; ++d) { lo[d] = expf(lo[d] - m); s += lo[d]; }
        const float inv = 1.f / s;
#pragma unroll
        for (int d = 0; d < 6; ++d) attn[h * 36 + cc * 6 + d] = lo[d] * inv;
    }
    __syncthreads();

    for (int idx = tid; idx < 48 * 48; idx += 256) {
        const int c = idx / 48, dg = idx % 48;
        const int h = dg / 6, hd = dg % 6;
        float s = 0.f;
#pragma unroll
        for (int cc = 0; cc < 6; ++cc)
            s = fmaf(proj_w[c * 48 + h * 6 + cc], attn[h * 36 + cc * 6 + hd], s);
        W2s[idx] = s;
    }
    __syncthreads();

    unsigned short* cb = cwb + (size_t)b * 27648;
    for (int pp = 0; pp < 9; ++pp) {
        const int pair = pp * 256 + tid;
        const int c = pair / 48, e = pair % 48;
        float acc[9];
#pragma unroll
        for (int t = 0; t < 9; ++t) acc[t] = 0.f;
        for (int d = 0; d < 48; ++d) {
            const float wv = W2s[c * 48 + d] * v_w[d * 48 + e];
#pragma unroll
            for (int t = 0; t < 9; ++t)
                acc[t] = fmaf(wv, v_dw[d * 9 + t], acc[t]);
        }
#pragma unroll
        for (int t = 0; t < 9; ++t)
            cb[(size_t)((t * 3 + (e >> 4)) * 64 + c) * 16 + (e & 15)] = f2bf(acc[t]);
    }
    // pad slots 48..63 -> zero  (27*16*16 = 6912 elems)
    for (int i = tid; i < 6912; i += 256) {
        const int e16 = i & 15;
        const int cp = 48 + ((i >> 4) & 15);
        const int tk = i >> 8;
        cb[(size_t)(tk * 64 + cp) * 16 + e16] = 0;
    }
}

// ---------------------------------------------------------------------------
// K3: out = cw (*) fea1, 32x8 tile, 256 thr (4 waves).
//  wave: m = w&1 (32 of 64 M-slots), g = w>>1 (rows 4g..4g+3). 4 accums.
// ---------------------------------------------------------------------------
__global__ __launch_bounds__(256, 4) void conv3x3_out_kernel(
    const float* __restrict__ fea1, const unsigned short* __restrict__ cwb,
    float* __restrict__ out) {
    __shared__ __align__(16) unsigned short xs[HP2][XSP];

    const int tid = threadIdx.x;
    const int b = blockIdx.y;
    const int tile = xcd_map(blockIdx.x, NTILE);
    const int tx = tile & 7, ty = tile >> 3;
    const float* fb = fea1 + (size_t)b * 48 * HW;
    const unsigned short* cb = cwb + (size_t)b * 27648;

    const int wave = tid >> 6, lane = tid & 63;
    const int l31 = lane & 31, lhi = lane >> 5;
    const int m = wave & 1, g = wave >> 1;

    f32x16 C[4];
#pragma unroll
    for (int nf = 0; nf < 4; ++nf)
#pragma unroll
        for (int r = 0; r < 16; ++r) C[nf][r] = 0.f;

#pragma unroll
    for (int ks = 0; ks < 3; ++ks) {
        __syncthreads();
        for (int hp = tid; hp < HP2; hp += 256) {
            const int hx = hp % HAW, hy = hp / HAW;
            const int gx = tx * TW + hx - 1, gy = ty * TH + hy - 1;
            const bool inb = ((unsigned)gx < (unsigned)IMG) && ((unsigned)gy < (unsigned)IMG);
            const int pix = inb ? (gy * IMG + gx) : 0;
            bf16x8 t0, t1;
#pragma unroll
            for (int c = 0; c < 8; ++c) {
                t0[c] = (short)f2bf(inb ? fb[(size_t)(ks * 16 + c) * HW + pix] : 0.f);
                t1[c] = (short)f2bf(inb ? fb[(size_t)(ks * 16 + 8 + c) * HW + pix] : 0.f);
            }
            *(bf16x8*)&xs[hp][0] = t0;
            *(bf16x8*)&xs[hp][8] = t1;
        }
        __syncthreads();

#pragma unroll
        for (int tap = 0; tap < 9; ++tap) {
            const int dy = tap / 3, dx = tap % 3;
            const bf16x8 a = *(const bf16x8*)&cb[(size_t)((tap * 3 + ks) * 64 + m * 32 + l31) * 16 + lhi * 8];
#pragma unroll
            for (int nf = 0; nf < 4; ++nf) {
                const int hrow = (4 * g + nf + dy) * HAW + l31 + dx;
                const bf16x8 bb = *(const bf16x8*)&xs[hrow][lhi * 8];
                C[nf] = __builtin_amdgcn_mfma_f32_32x32x16_bf16(a, bb, C[nf], 0, 0, 0);
            }
        }
    }

    float* ob = out + (size_t)b * 48 * HW;
#pragma unroll
    for (int nf = 0; nf < 4; ++nf) {
        const int gpx = (ty * TH + 4 * g + nf) * IMG + tx * TW + l31;
#pragma unroll
        for (int r = 0; r < 16; ++r) {
            const int och = m * 32 + (r & 3) + 8 * (r >> 2) + 4 * lhi;
            if (m == 0 || r < 8) ob[(size_t)och * HW + gpx] = C[nf][r];
        }
    }
}

// ---------------------------------------------------------------------------
extern "C" void kernel_launch(void* const* d_in, const int* in_sizes, int n_in,
                              void* d_out, int out_size, void* d_ws, size_t ws_size,
                              hipStream_t stream) {
    const float* fea0 = (const float*)d_in[0];
    const float* fea1 = (const float*)d_in[1];
    const float* qk_w = (const float*)d_in[2];
    const float* qk_dw = (const float*)d_in[3];
    const float* v_w = (const float*)d_in[4];
    const float* v_dw = (const float*)d_in[5];
    const float* proj_w = (const float*)d_in[6];
    const float* temperature = (const float*)d_in[7];
    float* out = (float*)d_out;

    char* ws = (char*)d_ws;
    float* stats = (float*)ws;                                     // 6144 B
    unsigned short* cwb = (unsigned short*)(ws + 8192);            // 221184 B
    unsigned short* qcwb = (unsigned short*)(ws + 8192 + 221184);  // 110592 B

    hipMemsetAsync(stats, 0, (size_t)NB * 384 * sizeof(float), stream);

    prep_qcw_kernel<<<216, 256, 0, stream>>>(qk_w, qk_dw, qcwb);
    fused_qk_stats_kernel<<<dim3(2 * NTILE, NB), 256, 0, stream>>>(fea0, qcwb, stats);
    softmax_w2_cw_kernel<<<NB, 256, 0, stream>>>(stats, proj_w, temperature, v_w, v_dw, cwb);
    conv3x3_out_kernel<<<dim3(NTILE, NB), 256, 0, stream>>>(fea1, cwb, out);
}